// Round 5
// baseline (11.360 us; speedup 1.0000x reference)
//
#include <hip/hip_runtime.h>
#include <math.h>

// Problem constants
#define T_LEN   8192
#define D_DIM   128
#define NTHR    256                // 4 waves per block
#define NBLK    32                 // 256 outputs per block
#define OPB     256
#define NTAP    32                 // rho in [-16,15]; tails underflow f32 (R2-R4: absmax 0.0)
#define GAUSS_C 0.39894228f

// ws layout: float2 pmm[128] (per-wave {min,max}), then float psedu[T_LEN]

__global__ __launch_bounds__(NTHR) void k_conv(
    const float* __restrict__ X, const float* __restrict__ weight,
    const float* __restrict__ noise, const float* __restrict__ sigma,
    float* __restrict__ psedu, float2* __restrict__ pmm)
{
    __shared__ float wsc[D_DIM];    // e_d * C / sigma_d (unnormalized; /S folded into epilogue)
    __shared__ float inv2[D_DIM];   // 1/(2 sigma_d^2)
    __shared__ float g2[NTAP];      // combined taps: g2[k] = g(rho = 15-k)
    __shared__ float s[OPB + NTAP]; // spike window (288)
    __shared__ float redS[2];       // exp-sum partials (threads 0..127 = 2 waves)

    const int tid = threadIdx.x;
    const int bid = blockIdx.x;
    const int B0  = bid * OPB;
    const int t   = B0 + tid;

    // ---- global loads up front (branchless, clamped) ----
    const int   i  = B0 - 16 + tid;             // max 8175 < T_LEN
    const float x  = X[max(i, 0)];
    const float nz = noise[t];
    s[tid] = (x > 0.5f && i >= 0) ? 1.f : 0.f;
    if (tid < OPB + NTAP - NTHR) {              // 32 extra spikes
        const int   i2 = B0 - 16 + NTHR + tid;  // can exceed T_LEN-1 in last block
        const float x2 = X[min(i2, T_LEN - 1)];
        s[NTHR + tid] = (x2 > 0.5f && i2 < T_LEN) ? 1.f : 0.f;
    }

    // ---- unnormalized softmax weights; S via shfl (threads 0..127) ----
    if (tid < D_DIM) {
        const float w  = weight[tid];
        const float sg = sigma[tid];
        const float e  = __expf(w);
        wsc[tid]  = e * (GAUSS_C / sg);
        inv2[tid] = 1.f / (2.f * sg * sg);
        float S = e;
        #pragma unroll
        for (int off = 32; off >= 1; off >>= 1) S += __shfl_xor(S, off);
        if ((tid & 63) == 0) redS[tid >> 6] = S;
    }
    __syncthreads();                            // covers s, wsc, inv2, redS
    const float invS = 1.f / (redS[0] + redS[1]);

    // ---- combined taps: tap k = tid>>3, 16 channels per thread ----
    {
        const int   k   = tid >> 3;
        const int   c   = (tid & 7) * 16;
        const float rho = (float)(15 - k);
        const float r2  = rho * rho;
        float a = 0.f;
        #pragma unroll
        for (int q = 0; q < 4; ++q) {
            float4 wa = *reinterpret_cast<const float4*>(&wsc[c + 4*q]);
            float4 ia = *reinterpret_cast<const float4*>(&inv2[c + 4*q]);
            a = fmaf(wa.x, __expf(-r2 * ia.x), a);
            a = fmaf(wa.y, __expf(-r2 * ia.y), a);
            a = fmaf(wa.z, __expf(-r2 * ia.z), a);
            a = fmaf(wa.w, __expf(-r2 * ia.w), a);
        }
        a += __shfl_xor(a, 1);
        a += __shfl_xor(a, 2);
        a += __shfl_xor(a, 4);
        if ((tid & 7) == 0) g2[k] = a;
    }
    __syncthreads();

    // ---- 32-tap conv: psedu[t] = (sum_k s[tid+k] * g2[k]) * invS + noise[t] ----
    float g2r[NTAP];
    #pragma unroll
    for (int q = 0; q < 8; ++q) {
        float4 v = *reinterpret_cast<const float4*>(&g2[4*q]);
        g2r[4*q+0] = v.x; g2r[4*q+1] = v.y; g2r[4*q+2] = v.z; g2r[4*q+3] = v.w;
    }
    float a0 = 0.f, a1 = 0.f, a2 = 0.f, a3 = 0.f;
    #pragma unroll
    for (int k = 0; k < NTAP; k += 4) {
        a0 = fmaf(s[tid + k    ], g2r[k    ], a0);
        a1 = fmaf(s[tid + k + 1], g2r[k + 1], a1);
        a2 = fmaf(s[tid + k + 2], g2r[k + 2], a2);
        a3 = fmaf(s[tid + k + 3], g2r[k + 3], a3);
    }
    const float acc = fmaf((a0 + a1) + (a2 + a3), invS, nz);
    psedu[t] = acc;

    // ---- per-wave min/max straight to global (no cross-wave combine) ----
    float mn = acc, mx = acc;
    #pragma unroll
    for (int off = 32; off >= 1; off >>= 1) {
        mn = fminf(mn, __shfl_xor(mn, off));
        mx = fmaxf(mx, __shfl_xor(mx, off));
    }
    if ((tid & 63) == 0) pmm[bid * 4 + (tid >> 6)] = make_float2(mn, mx);
}

__global__ __launch_bounds__(NTHR) void k_norm(
    const float* __restrict__ psedu, const float2* __restrict__ pmm,
    float* __restrict__ out)
{
    const int tid  = threadIdx.x;
    const int lane = tid & 63;
    const int t    = blockIdx.x * NTHR + tid;

    const float  p = psedu[t];                  // issues in parallel with pmm loads
    const float2 a = pmm[lane];
    const float2 b = pmm[lane + 64];
    float mn = fminf(a.x, b.x);
    float mx = fmaxf(a.y, b.y);
    #pragma unroll
    for (int off = 32; off >= 1; off >>= 1) {
        mn = fminf(mn, __shfl_xor(mn, off));
        mx = fmaxf(mx, __shfl_xor(mx, off));
    }
    out[t] = (p - mn) * (1.f / (mx - mn));
}

extern "C" void kernel_launch(void* const* d_in, const int* in_sizes, int n_in,
                              void* d_out, int out_size, void* d_ws, size_t ws_size,
                              hipStream_t stream) {
    const float* X      = (const float*)d_in[0];   // (1, 8192)
    const float* weight = (const float*)d_in[1];   // (1, 128)
    const float* noise  = (const float*)d_in[2];   // (1, 8192)
    const float* sigma  = (const float*)d_in[3];   // (128,)
    float* out = (float*)d_out;                    // (1, 8192) float32

    float2* pmm   = (float2*)d_ws;                 // 128 float2
    float*  psedu = (float*)d_ws + 256;            // 8192 floats

    k_conv<<<NBLK, NTHR, 0, stream>>>(X, weight, noise, sigma, psedu, pmm);
    k_norm<<<NBLK, NTHR, 0, stream>>>(psedu, pmm, out);
}

// Round 6
// 11.126 us; speedup vs baseline: 1.0211x; 1.0211x over previous
//
#include <hip/hip_runtime.h>
#include <math.h>

// Problem constants
#define T_LEN   8192
#define D_DIM   128
#define NTHR    128                // 2 waves per block (R4 config — measured best: 11.04us)
#define NBLK    64                 // 8192 / 128 outputs per block
#define OPB     128
#define NTAP    32                 // rho in [-16,15]; tails underflow f32 (R2-R5: absmax <= 5e-4)
#define GAUSS_C 0.39894228f

// ws layout: float2 pmm[128] (per-wave {min,max}), then float psedu[T_LEN]

__global__ __launch_bounds__(NTHR) void k_conv(
    const float* __restrict__ X, const float* __restrict__ weight,
    const float* __restrict__ noise, const float* __restrict__ sigma,
    float* __restrict__ psedu, float2* __restrict__ pmm)
{
    __shared__ float wsc[D_DIM];    // e_d * C / sigma_d  (unnormalized; /S folded into epilogue)
    __shared__ float inv2[D_DIM];   // 1/(2 sigma_d^2)
    __shared__ float g2[NTAP];      // combined taps: g2[k] = g(rho = 15-k)
    __shared__ float s[OPB + NTAP]; // spike window (160)
    __shared__ float redS[2];       // per-wave exp-sum partials

    const int tid = threadIdx.x;
    const int wv  = tid >> 6;
    const int bid = blockIdx.x;
    const int B0  = bid * OPB;
    const int t   = B0 + tid;

    // ---- issue all global loads up front (branchless, clamped) ----
    const int   i   = B0 - 16 + tid;            // max 8175 < T_LEN
    const float x   = X[max(i, 0)];
    const int   i2  = i + NTHR;                 // used by tid < 32
    const float x2  = X[min(i2, T_LEN - 1)];
    const float nz  = noise[t];
    const float w   = weight[tid];
    const float sg  = sigma[tid];

    s[tid] = (x > 0.5f && i >= 0) ? 1.f : 0.f;
    if (tid < OPB + NTAP - NTHR)
        s[NTHR + tid] = (x2 > 0.5f && i2 < T_LEN) ? 1.f : 0.f;

    // ---- unnormalized softmax weights; S reduced concurrently ----
    const float e = __expf(w);
    wsc[tid]  = e * (GAUSS_C / sg);
    inv2[tid] = 1.f / (2.f * sg * sg);
    float S = e;
    #pragma unroll
    for (int off = 32; off >= 1; off >>= 1) S += __shfl_xor(S, off);
    if ((tid & 63) == 0) redS[wv] = S;
    __syncthreads();                             // covers wsc/inv2/s/redS
    const float invS = 1.f / (redS[0] + redS[1]);

    // ---- combined taps: tap k = tid>>2, 32 channels per lane-group ----
    {
        const int   k   = tid >> 2;
        const int   c   = (tid & 3) * 32;
        const float rho = (float)(15 - k);
        const float r2  = rho * rho;
        float a = 0.f;
        #pragma unroll
        for (int q = 0; q < 8; ++q) {
            float4 wa = *reinterpret_cast<const float4*>(&wsc[c + 4*q]);
            float4 ia = *reinterpret_cast<const float4*>(&inv2[c + 4*q]);
            a = fmaf(wa.x, __expf(-r2 * ia.x), a);
            a = fmaf(wa.y, __expf(-r2 * ia.y), a);
            a = fmaf(wa.z, __expf(-r2 * ia.z), a);
            a = fmaf(wa.w, __expf(-r2 * ia.w), a);
        }
        a += __shfl_xor(a, 1);
        a += __shfl_xor(a, 2);
        if ((tid & 3) == 0) g2[k] = a;
    }
    __syncthreads();

    // ---- 32-tap conv, 4-way acc split (serial chain 32 -> 8 FMA) ----
    float g2r[NTAP];
    #pragma unroll
    for (int q = 0; q < 8; ++q) {
        float4 v = *reinterpret_cast<const float4*>(&g2[4*q]);
        g2r[4*q+0] = v.x; g2r[4*q+1] = v.y; g2r[4*q+2] = v.z; g2r[4*q+3] = v.w;
    }
    float a0 = 0.f, a1 = 0.f, a2 = 0.f, a3 = 0.f;
    #pragma unroll
    for (int k = 0; k < NTAP; k += 4) {
        a0 = fmaf(s[tid + k    ], g2r[k    ], a0);
        a1 = fmaf(s[tid + k + 1], g2r[k + 1], a1);
        a2 = fmaf(s[tid + k + 2], g2r[k + 2], a2);
        a3 = fmaf(s[tid + k + 3], g2r[k + 3], a3);
    }
    const float acc = fmaf((a0 + a1) + (a2 + a3), invS, nz);
    psedu[t] = acc;

    // ---- per-wave min/max straight to global (no cross-wave combine) ----
    float mn = acc, mx = acc;
    #pragma unroll
    for (int off = 32; off >= 1; off >>= 1) {
        mn = fminf(mn, __shfl_xor(mn, off));
        mx = fmaxf(mx, __shfl_xor(mx, off));
    }
    if ((tid & 63) == 0) pmm[bid * 2 + wv] = make_float2(mn, mx);
}

__global__ __launch_bounds__(NTHR) void k_norm(
    const float* __restrict__ psedu, const float2* __restrict__ pmm,
    float* __restrict__ out)
{
    const int tid  = threadIdx.x;
    const int lane = tid & 63;
    const int t    = blockIdx.x * NTHR + tid;

    const float  p = psedu[t];                  // issues in parallel with pmm loads
    const float2 a = pmm[lane];
    const float2 b = pmm[lane + 64];
    float mn = fminf(a.x, b.x);
    float mx = fmaxf(a.y, b.y);
    #pragma unroll
    for (int off = 32; off >= 1; off >>= 1) {
        mn = fminf(mn, __shfl_xor(mn, off));
        mx = fmaxf(mx, __shfl_xor(mx, off));
    }
    out[t] = (p - mn) * (1.f / (mx - mn));
}

extern "C" void kernel_launch(void* const* d_in, const int* in_sizes, int n_in,
                              void* d_out, int out_size, void* d_ws, size_t ws_size,
                              hipStream_t stream) {
    const float* X      = (const float*)d_in[0];   // (1, 8192)
    const float* weight = (const float*)d_in[1];   // (1, 128)
    const float* noise  = (const float*)d_in[2];   // (1, 8192)
    const float* sigma  = (const float*)d_in[3];   // (128,)
    float* out = (float*)d_out;                    // (1, 8192) float32

    float2* pmm   = (float2*)d_ws;                 // 128 float2
    float*  psedu = (float*)d_ws + 256;            // 8192 floats

    k_conv<<<NBLK, NTHR, 0, stream>>>(X, weight, noise, sigma, psedu, pmm);
    k_norm<<<NBLK, NTHR, 0, stream>>>(psedu, pmm, out);
}